// Round 2
// baseline (1392.396 us; speedup 1.0000x reference)
//
#include <hip/hip_runtime.h>
#include <stdint.h>

// NNCLR forward on MI355X — round 2: MFMA bf16 filter + exact fp32 rescore.
//
// Pipeline (MFMA path):
//  k0_qprep   : queue fp32 -> Qhi bf16 (ws) + fused FIFO copy queue[:-512] -> new_queue[512:]
//  k1_norm    : P = l2norm([p1;p2]) -> Pn, PnT, Phi(bf16); p1n -> new_queue[0:512]
//  k2_mfma    : bf16 MFMA P·Qᵀ, per-(row, 128-col tile) packed max -> cand[1024][512]
//  k2b_rowmax : per-row max of cand -> rowbest (+ provisional nnidx)
//  k2c_rescore: fp32 rescore of all tiles with bf16max >= rowmax-0.05 -> exact nnidx
//  k3_sim     : S1 = 10*nn1·p2ᵀ, S2 = 10*nn2·p1ᵀ
//  k4_loss    : loss rows = LSE(row/col of S) - diag
//
// Margin justification: per-element bf16 RNE err <= 2^-9 rel; dot err <= 2^-8 * sum|x_i y_i|
// <= 2^-8 = 3.9e-3 (unit vectors, Cauchy-Schwarz). True fp32 argmax column's bf16 score is
// >= rowmax_bf16 - 2*3.9e-3; margin 0.05 gives ~6x slack. Final argmax decided on fp32 dots.

#define BATCH  512
#define DIM    256
#define QUEUE  65536
#define MROWS  1024
#define NTILE  512           // 65536 / 128
#define MARGIN 0.05f

typedef short bf16x8 __attribute__((ext_vector_type(8)));
typedef float f32x4  __attribute__((ext_vector_type(4)));

#define GLOAD16(g, l) __builtin_amdgcn_global_load_lds( \
    (const __attribute__((address_space(1))) unsigned int*)(g), \
    (__attribute__((address_space(3))) unsigned int*)(l), 16, 0, 0)

__device__ __forceinline__ unsigned int mono_f32(float f) {
    unsigned int u = __float_as_uint(f);
    return (u & 0x80000000u) ? ~u : (u | 0x80000000u);
}
__device__ __forceinline__ float unmono_f32(unsigned int m) {
    unsigned int u = (m & 0x80000000u) ? (m ^ 0x80000000u) : ~m;
    return __uint_as_float(u);
}
__device__ __forceinline__ unsigned short f2bf(float f) {   // RNE fp32->bf16
    unsigned int u = __float_as_uint(f);
    return (unsigned short)((u + 0x7fffu + ((u >> 16) & 1u)) >> 16);
}

// ---------------- k0: queue -> bf16 + FIFO copy ----------------
__global__ void k0_qprep(const float* __restrict__ queue, unsigned short* __restrict__ Qhi,
                         float* __restrict__ outq)
{
    const int f = blockIdx.x * 256 + threadIdx.x;   // float4 index, 0..65536*64-1
    float4 v = ((const float4*)queue)[f];
    short4 b;
    b.x = (short)f2bf(v.x); b.y = (short)f2bf(v.y);
    b.z = (short)f2bf(v.z); b.w = (short)f2bf(v.w);
    ((short4*)Qhi)[f] = b;
    if (f < (QUEUE - BATCH) * (DIM / 4))
        ((float4*)(outq + (size_t)BATCH * DIM))[f] = v;   // new_queue[512:] = queue[:-512]
}

// ---------------- k1: normalize ----------------
__global__ void k1_norm(const float* __restrict__ p1, const float* __restrict__ p2,
                        float* __restrict__ Pn, float* __restrict__ PnT,
                        unsigned short* __restrict__ Phi, float* __restrict__ outq)
{
    const int r = blockIdx.x;        // 0..1023
    const int t = threadIdx.x;       // 0..63
    const float* src = (r < BATCH) ? p1 : p2;
    const int row = (r < BATCH) ? r : r - BATCH;
    float4 v = ((const float4*)(src + (size_t)row * DIM))[t];
    float sq = v.x*v.x + v.y*v.y + v.z*v.z + v.w*v.w;
    #pragma unroll
    for (int off = 32; off; off >>= 1) sq += __shfl_xor(sq, off, 64);
    sq = fmaxf(sq, 1e-12f);
    float s = rsqrtf(sq);
    s = s * (1.5f - 0.5f * sq * s * s);
    v.x *= s; v.y *= s; v.z *= s; v.w *= s;
    ((float4*)(Pn + (size_t)r * DIM))[t] = v;
    const int k = t * 4;
    PnT[(size_t)(k + 0) * MROWS + r] = v.x;
    PnT[(size_t)(k + 1) * MROWS + r] = v.y;
    PnT[(size_t)(k + 2) * MROWS + r] = v.z;
    PnT[(size_t)(k + 3) * MROWS + r] = v.w;
    if (Phi) {
        short4 b;
        b.x = (short)f2bf(v.x); b.y = (short)f2bf(v.y);
        b.z = (short)f2bf(v.z); b.w = (short)f2bf(v.w);
        ((short4*)Phi)[(size_t)r * (DIM / 4) + t] = b;
    }
    if (r < BATCH) ((float4*)(outq + (size_t)r * DIM))[t] = v;
}

// ---------------- k2: bf16 MFMA filter (hot) ----------------
// 128x128 tile, 4 waves of 64x64, BK=32, 16x16x32 MFMA, global_load_lds width-16 staging.
__global__ __launch_bounds__(256, 3)
void k2_mfma(const unsigned short* __restrict__ Phi, const unsigned short* __restrict__ Qhi,
             unsigned long long* __restrict__ cand)
{
    __shared__ short As[128 * 32];                 // 8 KB  [m 0..127][k 0..31]
    __shared__ short Bs[128 * 32];                 // 8 KB  [n 0..127][k 0..31]
    __shared__ unsigned long long red[128 * 2];    // 2 KB

    const int g  = blockIdx.x;
    const int mt = g & 7, nt = g >> 3;             // n-strip-major: 8 m-tiles share L2 strip
    const int m0 = mt * 128, n0 = nt * 128;
    const int t  = threadIdx.x;
    const int w  = t >> 6, lid = t & 63;
    const int wm = w & 1, wn = w >> 1;
    const int lr = lid & 15, q = lid >> 4;

    // staging addresses: thread t loads 16B chunk (row=t>>2, c=t&3) per inst
    const unsigned short* gA0 = Phi + (size_t)(m0 + (t >> 2)) * DIM + (t & 3) * 8;
    const unsigned short* gB0 = Qhi + (size_t)(n0 + (t >> 2)) * DIM + (t & 3) * 8;
    char* lA = (char*)As + t * 16;
    char* lB = (char*)Bs + t * 16;

    f32x4 acc[4][4];
    #pragma unroll
    for (int i = 0; i < 4; ++i)
        #pragma unroll
        for (int j = 0; j < 4; ++j) acc[i][j] = (f32x4){0.f, 0.f, 0.f, 0.f};

    const short* aBase = As + (wm * 64 + lr) * 32 + q * 8;
    const short* bBase = Bs + (wn * 64 + lr) * 32 + q * 8;

    for (int kb = 0; kb < 8; ++kb) {
        __syncthreads();                                    // prev compute done reading LDS
        GLOAD16(gA0 + kb * 32, lA);
        GLOAD16(gA0 + kb * 32 + 64 * DIM, lA + 4096);
        GLOAD16(gB0 + kb * 32, lB);
        GLOAD16(gB0 + kb * 32 + 64 * DIM, lB + 4096);
        __syncthreads();                                    // drains vmcnt -> LDS visible
        bf16x8 a[4], b[4];
        #pragma unroll
        for (int mi = 0; mi < 4; ++mi) a[mi] = *(const bf16x8*)(aBase + mi * 512);
        #pragma unroll
        for (int ni = 0; ni < 4; ++ni) b[ni] = *(const bf16x8*)(bBase + ni * 512);
        #pragma unroll
        for (int mi = 0; mi < 4; ++mi)
            #pragma unroll
            for (int ni = 0; ni < 4; ++ni)
                acc[mi][ni] = __builtin_amdgcn_mfma_f32_16x16x32_bf16(a[mi], b[ni], acc[mi][ni], 0, 0, 0);
    }

    // Epilogue: per-row packed max over this WG's 128 cols.
    // C/D layout: col = lane&15, row = (lane>>4)*4 + reg  (m89/m91-verified)
    #pragma unroll
    for (int mi = 0; mi < 4; ++mi) {
        #pragma unroll
        for (int reg = 0; reg < 4; ++reg) {
            unsigned long long best = 0ull;
            #pragma unroll
            for (int ni = 0; ni < 4; ++ni) {
                int col = n0 + wn * 64 + ni * 16 + lr;
                unsigned long long pk = ((unsigned long long)mono_f32(acc[mi][ni][reg]) << 32)
                                      | (unsigned int)(65535 - col);
                best = best > pk ? best : pk;
            }
            #pragma unroll
            for (int off = 1; off <= 8; off <<= 1) {   // reduce over lane&15 (cols)
                unsigned long long o = __shfl_xor(best, off, 64);
                best = best > o ? best : o;
            }
            if (lr == 0) red[(wm * 64 + mi * 16 + q * 4 + reg) * 2 + wn] = best;
        }
    }
    __syncthreads();
    if (t < 128) {
        unsigned long long b0 = red[t * 2], b1 = red[t * 2 + 1];
        cand[(size_t)(m0 + t) * NTILE + nt] = b0 > b1 ? b0 : b1;
    }
}

// ---------------- k2b: per-row max of candidates ----------------
__global__ void k2b_rowmax(const unsigned long long* __restrict__ cand, int n,
                           unsigned long long* __restrict__ rowbest, int* __restrict__ nnidx)
{
    const int row = blockIdx.x;      // 0..1023
    const int t = threadIdx.x;       // 64
    unsigned long long best = 0ull;
    for (int i = t; i < n; i += 64) {
        unsigned long long c = cand[(size_t)row * n + i];
        best = best > c ? best : c;
    }
    #pragma unroll
    for (int off = 1; off < 64; off <<= 1) {
        unsigned long long o = __shfl_xor(best, off, 64);
        best = best > o ? best : o;
    }
    if (t == 0) {
        rowbest[row] = best;
        nnidx[row] = 65535 - (int)(best & 0xFFFFull);   // exact in fp32 fallback path
    }
}

// ---------------- k2c: exact fp32 rescore of near-max tiles ----------------
__global__ void k2c_rescore(const unsigned long long* __restrict__ cand,
                            const unsigned long long* __restrict__ rowbest,
                            const float* __restrict__ Pn, const float* __restrict__ queue,
                            int* __restrict__ nnidx)
{
    const int row = blockIdx.x;      // 0..1023
    const int t = threadIdx.x;       // 256
    __shared__ float prow[DIM];
    __shared__ float partial[128];
    __shared__ int cnt;
    __shared__ unsigned short tl[NTILE];
    __shared__ unsigned long long wred[4];
    if (t == 0) cnt = 0;
    prow[t] = Pn[(size_t)row * DIM + t];
    __syncthreads();
    const unsigned int thrm = mono_f32(unmono_f32((unsigned int)(rowbest[row] >> 32)) - MARGIN);
    for (int c = t; c < NTILE; c += 256)
        if ((unsigned int)(cand[(size_t)row * NTILE + c] >> 32) >= thrm)
            tl[atomicAdd(&cnt, 1)] = (unsigned short)c;
    __syncthreads();
    const int nc = cnt;                               // uniform
    const int col_l = t & 127, kh = t >> 7;
    unsigned long long best = 0ull;
    for (int li = 0; li < nc; ++li) {
        const int col = tl[li] * 128 + col_l;
        const float* qr = queue + (size_t)col * DIM + kh * 128;
        const float* pr = prow + kh * 128;
        float s = 0.f;
        #pragma unroll 8
        for (int k = 0; k < 128; ++k) s = fmaf(pr[k], qr[k], s);
        if (kh) partial[col_l] = s;
        __syncthreads();
        if (!kh) {
            float v = s + partial[col_l];
            unsigned long long pk = ((unsigned long long)mono_f32(v) << 32)
                                  | (unsigned int)(65535 - col);
            best = best > pk ? best : pk;
        }
        __syncthreads();
    }
    #pragma unroll
    for (int off = 1; off < 64; off <<= 1) {
        unsigned long long o = __shfl_xor(best, off, 64);
        best = best > o ? best : o;
    }
    if ((t & 63) == 0) wred[t >> 6] = best;
    __syncthreads();
    if (t == 0) {
        #pragma unroll
        for (int ww = 1; ww < 4; ++ww) best = best > wred[ww] ? best : wred[ww];
        nnidx[row] = 65535 - (int)(best & 0xFFFFull);
    }
}

// ---------------- fp32 fallback NN kernel (round-1, only if ws too small) ----------------
__global__ __launch_bounds__(256, 2)
void k2_fp32(const float* __restrict__ Pn, const float* __restrict__ queue,
             float* __restrict__ outq, unsigned long long* __restrict__ cand)
{
    __shared__ float Qt[DIM * 64];
    const int wg = blockIdx.x, n0 = wg * 64, tid = threadIdx.x;
    #pragma unroll
    for (int it = 0; it < 16; ++it) {
        int idx = tid + it * 256;
        int row = idx & 63, k4 = idx >> 6;
        float4 v = ((const float4*)(queue + (size_t)(n0 + row) * DIM))[k4];
        Qt[(k4 * 4 + 0) * 64 + row] = v.x; Qt[(k4 * 4 + 1) * 64 + row] = v.y;
        Qt[(k4 * 4 + 2) * 64 + row] = v.z; Qt[(k4 * 4 + 3) * 64 + row] = v.w;
        int qrow = n0 + row;
        if (qrow < QUEUE - BATCH)
            ((float4*)(outq + (size_t)(qrow + BATCH) * DIM))[k4] = v;
    }
    __syncthreads();
    const int tx = tid & 15, ty = tid >> 4;
    const float4* Pn4 = (const float4*)Pn;
    const float4* Qt4 = (const float4*)Qt;
    for (int mtl = 0; mtl < MROWS / 128; ++mtl) {
        const int m0 = mtl * 128;
        float acc[8][4];
        #pragma unroll
        for (int i = 0; i < 8; ++i)
            #pragma unroll
            for (int j = 0; j < 4; ++j) acc[i][j] = 0.f;
        for (int k4 = 0; k4 < 64; ++k4) {
            float4 bv[4];
            #pragma unroll
            for (int kk = 0; kk < 4; ++kk) bv[kk] = Qt4[(k4 * 4 + kk) * 16 + tx];
            float4 a[8];
            #pragma unroll
            for (int i = 0; i < 8; ++i) a[i] = Pn4[(size_t)(m0 + ty * 8 + i) * 64 + k4];
            #pragma unroll
            for (int i = 0; i < 8; ++i) {
                float av[4] = {a[i].x, a[i].y, a[i].z, a[i].w};
                #pragma unroll
                for (int kk = 0; kk < 4; ++kk) {
                    acc[i][0] = fmaf(av[kk], bv[kk].x, acc[i][0]);
                    acc[i][1] = fmaf(av[kk], bv[kk].y, acc[i][1]);
                    acc[i][2] = fmaf(av[kk], bv[kk].z, acc[i][2]);
                    acc[i][3] = fmaf(av[kk], bv[kk].w, acc[i][3]);
                }
            }
        }
        #pragma unroll
        for (int i = 0; i < 8; ++i) {
            unsigned long long best = 0ull;
            #pragma unroll
            for (int j = 0; j < 4; ++j) {
                unsigned long long pk = ((unsigned long long)mono_f32(acc[i][j]) << 32)
                                      | (unsigned int)(65535 - (n0 + tx * 4 + j));
                best = best > pk ? best : pk;
            }
            #pragma unroll
            for (int off = 1; off <= 8; off <<= 1) {
                unsigned long long o = __shfl_xor(best, off, 64);
                best = best > o ? best : o;
            }
            if (tx == 0) cand[(size_t)(m0 + ty * 8 + i) * 1024 + wg] = best;
        }
    }
}

// ---------------- k3: S1/S2 similarity matrices ----------------
__global__ void k3_sim(const int* __restrict__ nnidx, const float* __restrict__ queue,
                       const float* __restrict__ PnT, float* __restrict__ S)
{
    const int b = blockIdx.x;
    const int tid = threadIdx.x;     // 256
    const int which = (b < BATCH) ? 0 : 1;
    const int i = which ? b - BATCH : b;
    const int idx = nnidx[which ? BATCH + i : i];
    const int colbase = which ? 0 : BATCH;
    __shared__ float nnv[DIM];
    nnv[tid] = queue[(size_t)idx * DIM + tid];
    __syncthreads();
    float acc0 = 0.f, acc1 = 0.f;
    #pragma unroll 4
    for (int k = 0; k < DIM; ++k) {
        const float nv = nnv[k];
        const float* rowp = PnT + (size_t)k * MROWS + colbase;
        acc0 = fmaf(nv, rowp[tid], acc0);
        acc1 = fmaf(nv, rowp[tid + 256], acc1);
    }
    float* Sout = S + (size_t)which * (BATCH * BATCH) + (size_t)i * BATCH;
    Sout[tid]       = acc0 * 10.0f;
    Sout[tid + 256] = acc1 * 10.0f;
}

// ---------------- k4: loss ----------------
__global__ void k4_loss(const float* __restrict__ S, float* __restrict__ loss)
{
    const int r = blockIdx.x;        // 0..2047
    const int tid = threadIdx.x;     // 256
    const int grp = r >> 9;
    const int i = r & 511;
    const float* M = S + (size_t)(grp >> 1) * (BATCH * BATCH);
    float x0, x1;
    if (!(grp & 1)) { x0 = M[(size_t)i * BATCH + tid];  x1 = M[(size_t)i * BATCH + tid + 256]; }
    else            { x0 = M[(size_t)tid * BATCH + i];  x1 = M[(size_t)(tid + 256) * BATCH + i]; }
    const float diag = M[(size_t)i * BATCH + i];
    float mx = fmaxf(x0, x1);
    #pragma unroll
    for (int off = 1; off < 64; off <<= 1) mx = fmaxf(mx, __shfl_xor(mx, off, 64));
    __shared__ float redm[4], reds[4];
    if ((tid & 63) == 0) redm[tid >> 6] = mx;
    __syncthreads();
    mx = fmaxf(fmaxf(redm[0], redm[1]), fmaxf(redm[2], redm[3]));
    float e = __expf(x0 - mx) + __expf(x1 - mx);
    #pragma unroll
    for (int off = 1; off < 64; off <<= 1) e += __shfl_xor(e, off, 64);
    if ((tid & 63) == 0) reds[tid >> 6] = e;
    __syncthreads();
    if (tid == 0)
        loss[r] = mx + logf(reds[0] + reds[1] + reds[2] + reds[3]) - diag;
}

// ---------------- launcher ----------------
extern "C" void kernel_launch(void* const* d_in, const int* in_sizes, int n_in,
                              void* d_out, int out_size, void* d_ws, size_t ws_size,
                              hipStream_t stream)
{
    const float* p1    = (const float*)d_in[0];
    const float* p2    = (const float*)d_in[1];
    const float* queue = (const float*)d_in[2];
    float* out  = (float*)d_out;
    float* loss = out;
    float* outq = out + 4 * BATCH;

    const size_t szQhi  = (size_t)QUEUE * DIM * 2;            // 32 MB
    const size_t szCand = (size_t)MROWS * NTILE * 8;          // 4 MB
    const size_t szRB   = (size_t)MROWS * 8;
    const size_t szPn   = (size_t)MROWS * DIM * 4;            // 1 MB
    const size_t szPhi  = (size_t)MROWS * DIM * 2;
    const size_t szS    = (size_t)2 * BATCH * BATCH * 4;      // 2 MB
    const size_t need   = szQhi + szCand + szRB + 2 * szPn + szPhi + szS + 4096;

    if (ws_size >= need) {
        char* w = (char*)d_ws;
        unsigned short* Qhi = (unsigned short*)w;              w += szQhi;
        unsigned long long* cand = (unsigned long long*)w;     w += szCand;
        unsigned long long* rowbest = (unsigned long long*)w;  w += szRB;
        float* Pn  = (float*)w;                                w += szPn;
        float* PnT = (float*)w;                                w += szPn;
        unsigned short* Phi = (unsigned short*)w;              w += szPhi;
        float* S = (float*)w;                                  w += szS;
        int* nnidx = (int*)w;

        hipLaunchKernelGGL(k0_qprep,    dim3(QUEUE * DIM / 4 / 256), dim3(256), 0, stream, queue, Qhi, outq);
        hipLaunchKernelGGL(k1_norm,     dim3(MROWS), dim3(64),  0, stream, p1, p2, Pn, PnT, Phi, outq);
        hipLaunchKernelGGL(k2_mfma,     dim3(8 * NTILE), dim3(256), 0, stream, Phi, Qhi, cand);
        hipLaunchKernelGGL(k2b_rowmax,  dim3(MROWS), dim3(64),  0, stream, cand, NTILE, rowbest, nnidx);
        hipLaunchKernelGGL(k2c_rescore, dim3(MROWS), dim3(256), 0, stream, cand, rowbest, Pn, queue, nnidx);
        hipLaunchKernelGGL(k3_sim,      dim3(MROWS), dim3(256), 0, stream, nnidx, queue, PnT, S);
        hipLaunchKernelGGL(k4_loss,     dim3(4 * BATCH), dim3(256), 0, stream, S, loss);
    } else {
        // fp32 fallback (round-1 path, ~674 us)
        char* w = (char*)d_ws;
        unsigned long long* cand = (unsigned long long*)w;     w += (size_t)MROWS * 1024 * 8;
        float* Pn  = (float*)w;                                w += szPn;
        float* PnT = (float*)w;                                w += szPn;
        float* S   = (float*)w;                                w += szS;
        int* nnidx = (int*)w;                                  w += 4096;
        unsigned long long* rowbest = (unsigned long long*)w;

        hipLaunchKernelGGL(k1_norm,    dim3(MROWS), dim3(64),  0, stream, p1, p2, Pn, PnT, (unsigned short*)nullptr, outq);
        hipLaunchKernelGGL(k2_fp32,    dim3(1024),  dim3(256), 0, stream, Pn, queue, outq, cand);
        hipLaunchKernelGGL(k2b_rowmax, dim3(MROWS), dim3(64),  0, stream, cand, 1024, rowbest, nnidx);
        hipLaunchKernelGGL(k3_sim,     dim3(MROWS), dim3(256), 0, stream, nnidx, queue, PnT, S);
        hipLaunchKernelGGL(k4_loss,    dim3(4 * BATCH), dim3(256), 0, stream, S, loss);
    }
}

// Round 3
// 425.804 us; speedup vs baseline: 3.2700x; 3.2700x over previous
//
#include <hip/hip_runtime.h>
#include <stdint.h>

// NNCLR forward on MI355X — round 3.
// Changes vs round 2:
//  * k2_mfma: LDS-free — MFMA fragments loaded directly from L2/L3-resident bf16 operands
//    (per-lane dwordx4 matches fragment layout). No K-loop barriers. 1024 blocks.
//  * rescore: MARGIN 0.05 -> 0.01 (still > 2*bf16 dot err bound 7.8e-3), and restructured:
//    k2c_list builds a compacted (row,tile) pair list; k2d_rescore does one block per pair
//    (grid-stride), fp32 dots, u64 atomicMax per row; k2e extracts nnidx.
//
// Numerical safety: let c* = fp32 argmax col. bf16(c*) >= fp32(c*) - e and
// rowmax_bf16 <= fp32(c*) + e with e <= 2^-8 (unit vectors) => bf16(c*) >= rowmax - 2e,
// 2e = 7.8e-3 < 0.01 margin => c*'s tile is always rescored. Final argmax decided in fp32.

#define BATCH  512
#define DIM    256
#define QUEUE  65536
#define MROWS  1024
#define NTILE  512           // 65536 / 128
#define MARGIN 0.01f

typedef short bf16x8 __attribute__((ext_vector_type(8)));
typedef float f32x4  __attribute__((ext_vector_type(4)));

__device__ __forceinline__ unsigned int mono_f32(float f) {
    unsigned int u = __float_as_uint(f);
    return (u & 0x80000000u) ? ~u : (u | 0x80000000u);
}
__device__ __forceinline__ float unmono_f32(unsigned int m) {
    unsigned int u = (m & 0x80000000u) ? (m ^ 0x80000000u) : ~m;
    return __uint_as_float(u);
}
__device__ __forceinline__ unsigned short f2bf(float f) {   // RNE fp32->bf16
    unsigned int u = __float_as_uint(f);
    return (unsigned short)((u + 0x7fffu + ((u >> 16) & 1u)) >> 16);
}

// ---------------- k0: queue -> bf16 + FIFO copy ----------------
__global__ void k0_qprep(const float* __restrict__ queue, unsigned short* __restrict__ Qhi,
                         float* __restrict__ outq)
{
    const int f = blockIdx.x * 256 + threadIdx.x;   // float4 index
    float4 v = ((const float4*)queue)[f];
    short4 b;
    b.x = (short)f2bf(v.x); b.y = (short)f2bf(v.y);
    b.z = (short)f2bf(v.z); b.w = (short)f2bf(v.w);
    ((short4*)Qhi)[f] = b;
    if (f < (QUEUE - BATCH) * (DIM / 4))
        ((float4*)(outq + (size_t)BATCH * DIM))[f] = v;   // new_queue[512:] = queue[:-512]
}

// ---------------- k1: normalize ----------------
__global__ void k1_norm(const float* __restrict__ p1, const float* __restrict__ p2,
                        float* __restrict__ Pn, float* __restrict__ PnT,
                        unsigned short* __restrict__ Phi, float* __restrict__ outq)
{
    const int r = blockIdx.x;        // 0..1023
    const int t = threadIdx.x;       // 0..63
    const float* src = (r < BATCH) ? p1 : p2;
    const int row = (r < BATCH) ? r : r - BATCH;
    float4 v = ((const float4*)(src + (size_t)row * DIM))[t];
    float sq = v.x*v.x + v.y*v.y + v.z*v.z + v.w*v.w;
    #pragma unroll
    for (int off = 32; off; off >>= 1) sq += __shfl_xor(sq, off, 64);
    sq = fmaxf(sq, 1e-12f);
    float s = rsqrtf(sq);
    s = s * (1.5f - 0.5f * sq * s * s);
    v.x *= s; v.y *= s; v.z *= s; v.w *= s;
    ((float4*)(Pn + (size_t)r * DIM))[t] = v;
    const int k = t * 4;
    PnT[(size_t)(k + 0) * MROWS + r] = v.x;
    PnT[(size_t)(k + 1) * MROWS + r] = v.y;
    PnT[(size_t)(k + 2) * MROWS + r] = v.z;
    PnT[(size_t)(k + 3) * MROWS + r] = v.w;
    short4 b;
    b.x = (short)f2bf(v.x); b.y = (short)f2bf(v.y);
    b.z = (short)f2bf(v.z); b.w = (short)f2bf(v.w);
    ((short4*)Phi)[(size_t)r * (DIM / 4) + t] = b;
    if (r < BATCH) ((float4*)(outq + (size_t)r * DIM))[t] = v;
}

// ---------------- k2: bf16 MFMA filter, LDS-free ----------------
// Block = (nt, m-half). 4 waves: wm = m-64-half, wn = n-64-half. Fragments loaded straight
// from global (A: Phi 0.5MB, L2-resident; B: this block's 64KB Qhi tile, L2 after first mt).
// A-frag layout: lane holds A[m=base+(l&15)][k = ks*32 + (l>>4)*8 ..+8] = 16B at row*512B.
__global__ __launch_bounds__(256, 4)
void k2_mfma(const unsigned short* __restrict__ Phi, const unsigned short* __restrict__ Qhi,
             unsigned long long* __restrict__ cand)
{
    __shared__ unsigned long long red[128 * 2];
    const int nt = blockIdx.x >> 1;
    const int mh = blockIdx.x & 1;
    const int n0 = nt * 128;
    const int t  = threadIdx.x;
    const int w  = t >> 6, lid = t & 63;
    const int wm = w & 1, wn = w >> 1;
    const int lr = lid & 15, q = lid >> 4;

    const unsigned short* Abase = Phi + (size_t)(wm * 64 + lr) * DIM + q * 8;
    const unsigned short* Bbase = Qhi + (size_t)(n0 + wn * 64 + lr) * DIM + q * 8;

    for (int mtl = 0; mtl < 4; ++mtl) {
        const int m0 = mh * 512 + mtl * 128;
        f32x4 acc[4][4];
        #pragma unroll
        for (int i = 0; i < 4; ++i)
            #pragma unroll
            for (int j = 0; j < 4; ++j) acc[i][j] = (f32x4){0.f, 0.f, 0.f, 0.f};

        #pragma unroll
        for (int ks = 0; ks < 8; ++ks) {
            bf16x8 a[4], b[4];
            #pragma unroll
            for (int mi = 0; mi < 4; ++mi)
                a[mi] = *(const bf16x8*)(Abase + ((size_t)(m0 + mi * 16) * DIM + ks * 32));
            #pragma unroll
            for (int ni = 0; ni < 4; ++ni)
                b[ni] = *(const bf16x8*)(Bbase + ((size_t)(ni * 16) * DIM + ks * 32));
            #pragma unroll
            for (int mi = 0; mi < 4; ++mi)
                #pragma unroll
                for (int ni = 0; ni < 4; ++ni)
                    acc[mi][ni] = __builtin_amdgcn_mfma_f32_16x16x32_bf16(a[mi], b[ni], acc[mi][ni], 0, 0, 0);
        }

        // Epilogue: per-row packed max over this block's 128 cols.
        // C/D layout: col = lane&15, row = (lane>>4)*4 + reg (validated round 2).
        __syncthreads();                      // red[] reuse guard (cheap: no vmem outstanding)
        #pragma unroll
        for (int mi = 0; mi < 4; ++mi) {
            #pragma unroll
            for (int reg = 0; reg < 4; ++reg) {
                unsigned long long best = 0ull;
                #pragma unroll
                for (int ni = 0; ni < 4; ++ni) {
                    int col = n0 + wn * 64 + ni * 16 + lr;
                    unsigned long long pk = ((unsigned long long)mono_f32(acc[mi][ni][reg]) << 32)
                                          | (unsigned int)(65535 - col);
                    best = best > pk ? best : pk;
                }
                #pragma unroll
                for (int off = 1; off <= 8; off <<= 1) {
                    unsigned long long o = __shfl_xor(best, off, 64);
                    best = best > o ? best : o;
                }
                if (lr == 0) red[(wm * 64 + mi * 16 + q * 4 + reg) * 2 + wn] = best;
            }
        }
        __syncthreads();
        if (t < 128) {
            unsigned long long b0 = red[t * 2], b1 = red[t * 2 + 1];
            cand[(size_t)(m0 + t) * NTILE + nt] = b0 > b1 ? b0 : b1;
        }
    }
}

// ---------------- k2b: per-row max + init ----------------
__global__ void k2b_rowmax(const unsigned long long* __restrict__ cand,
                           unsigned long long* __restrict__ rowbest,
                           unsigned long long* __restrict__ rowfinal,
                           int* __restrict__ npairs)
{
    const int row = blockIdx.x;      // 0..1023
    const int t = threadIdx.x;       // 64
    unsigned long long best = 0ull;
    for (int i = t; i < NTILE; i += 64) {
        unsigned long long c = cand[(size_t)row * NTILE + i];
        best = best > c ? best : c;
    }
    #pragma unroll
    for (int off = 1; off < 64; off <<= 1) {
        unsigned long long o = __shfl_xor(best, off, 64);
        best = best > o ? best : o;
    }
    if (t == 0) {
        rowbest[row] = best;
        rowfinal[row] = 0ull;        // ws is poisoned 0xAA every call — must re-init
        if (row == 0) *npairs = 0;
    }
}

// ---------------- k2c: compact candidate (row,tile) pairs ----------------
__global__ void k2c_list(const unsigned long long* __restrict__ cand,
                         const unsigned long long* __restrict__ rowbest,
                         unsigned int* __restrict__ pairs, int* __restrict__ npairs)
{
    const int idx = blockIdx.x * 256 + threadIdx.x;   // 0 .. 1024*512-1
    const int row = idx >> 9, tile = idx & 511;
    const unsigned int thrm = mono_f32(unmono_f32((unsigned int)(rowbest[row] >> 32)) - MARGIN);
    if ((unsigned int)(cand[idx] >> 32) >= thrm) {
        int p = atomicAdd(npairs, 1);
        pairs[p] = ((unsigned int)row << 16) | (unsigned int)tile;
    }
}

// ---------------- k2d: exact fp32 rescore, one block per pair ----------------
__global__ __launch_bounds__(256, 4)
void k2d_rescore(const unsigned int* __restrict__ pairs, const int* __restrict__ npairs,
                 const float* __restrict__ Pn, const float* __restrict__ queue,
                 unsigned long long* __restrict__ rowfinal)
{
    const int t = threadIdx.x;       // 256
    const int n = *npairs;
    __shared__ float prow[DIM];
    __shared__ float partial[128];
    for (int p = blockIdx.x; p < n; p += gridDim.x) {
        const unsigned int pr = pairs[p];
        const int row = pr >> 16, tile = pr & 0xffff;
        __syncthreads();                      // protect prow/partial reuse across iterations
        prow[t] = Pn[(size_t)row * DIM + t];  // blockDim == DIM
        __syncthreads();
        const int col_l = t & 127, kh = t >> 7;   // waves 0,1: kh=0 ; waves 2,3: kh=1
        const float4* q4 = (const float4*)(queue + ((size_t)tile * 128 + col_l) * DIM + kh * 128);
        const float4* p4 = (const float4*)(prow + kh * 128);
        float4 sv = {0.f, 0.f, 0.f, 0.f};
        #pragma unroll
        for (int k4 = 0; k4 < 32; ++k4) {
            float4 a = p4[k4], b = q4[k4];
            sv.x = fmaf(a.x, b.x, sv.x); sv.y = fmaf(a.y, b.y, sv.y);
            sv.z = fmaf(a.z, b.z, sv.z); sv.w = fmaf(a.w, b.w, sv.w);
        }
        float s = (sv.x + sv.y) + (sv.z + sv.w);
        if (kh) partial[col_l] = s;
        __syncthreads();
        if (!kh) {
            float v = s + partial[col_l];
            unsigned long long best = ((unsigned long long)mono_f32(v) << 32)
                                    | (unsigned int)(65535 - (tile * 128 + col_l));
            #pragma unroll
            for (int off = 1; off < 64; off <<= 1) {
                unsigned long long o = __shfl_xor(best, off, 64);
                best = best > o ? best : o;
            }
            if ((t & 63) == 0) atomicMax(rowfinal + row, best);
        }
    }
}

// ---------------- k2e: extract nn indices ----------------
__global__ void k2e_final(const unsigned long long* __restrict__ rowfinal, int* __restrict__ nnidx)
{
    const int i = blockIdx.x * 256 + threadIdx.x;
    if (i < MROWS) nnidx[i] = 65535 - (int)(rowfinal[i] & 0xFFFFull);
}

// ---------------- k3: S1/S2 similarity matrices ----------------
__global__ void k3_sim(const int* __restrict__ nnidx, const float* __restrict__ queue,
                       const float* __restrict__ PnT, float* __restrict__ S)
{
    const int b = blockIdx.x;
    const int tid = threadIdx.x;     // 256
    const int which = (b < BATCH) ? 0 : 1;
    const int i = which ? b - BATCH : b;
    const int idx = nnidx[which ? BATCH + i : i];
    const int colbase = which ? 0 : BATCH;
    __shared__ float nnv[DIM];
    nnv[tid] = queue[(size_t)idx * DIM + tid];
    __syncthreads();
    float acc0 = 0.f, acc1 = 0.f;
    #pragma unroll 4
    for (int k = 0; k < DIM; ++k) {
        const float nv = nnv[k];
        const float* rowp = PnT + (size_t)k * MROWS + colbase;
        acc0 = fmaf(nv, rowp[tid], acc0);
        acc1 = fmaf(nv, rowp[tid + 256], acc1);
    }
    float* Sout = S + (size_t)which * (BATCH * BATCH) + (size_t)i * BATCH;
    Sout[tid]       = acc0 * 10.0f;
    Sout[tid + 256] = acc1 * 10.0f;
}

// ---------------- k4: loss ----------------
__global__ void k4_loss(const float* __restrict__ S, float* __restrict__ loss)
{
    const int r = blockIdx.x;        // 0..2047
    const int tid = threadIdx.x;     // 256
    const int grp = r >> 9;
    const int i = r & 511;
    const float* M = S + (size_t)(grp >> 1) * (BATCH * BATCH);
    float x0, x1;
    if (!(grp & 1)) { x0 = M[(size_t)i * BATCH + tid];  x1 = M[(size_t)i * BATCH + tid + 256]; }
    else            { x0 = M[(size_t)tid * BATCH + i];  x1 = M[(size_t)(tid + 256) * BATCH + i]; }
    const float diag = M[(size_t)i * BATCH + i];
    float mx = fmaxf(x0, x1);
    #pragma unroll
    for (int off = 1; off < 64; off <<= 1) mx = fmaxf(mx, __shfl_xor(mx, off, 64));
    __shared__ float redm[4], reds[4];
    if ((tid & 63) == 0) redm[tid >> 6] = mx;
    __syncthreads();
    mx = fmaxf(fmaxf(redm[0], redm[1]), fmaxf(redm[2], redm[3]));
    float e = __expf(x0 - mx) + __expf(x1 - mx);
    #pragma unroll
    for (int off = 1; off < 64; off <<= 1) e += __shfl_xor(e, off, 64);
    if ((tid & 63) == 0) reds[tid >> 6] = e;
    __syncthreads();
    if (tid == 0)
        loss[r] = mx + logf(reds[0] + reds[1] + reds[2] + reds[3]) - diag;
}

// ---------------- launcher ----------------
extern "C" void kernel_launch(void* const* d_in, const int* in_sizes, int n_in,
                              void* d_out, int out_size, void* d_ws, size_t ws_size,
                              hipStream_t stream)
{
    const float* p1    = (const float*)d_in[0];
    const float* p2    = (const float*)d_in[1];
    const float* queue = (const float*)d_in[2];
    float* out  = (float*)d_out;
    float* loss = out;
    float* outq = out + 4 * BATCH;

    // Workspace layout (~42.6 MB; round 2 proved ws_size >= 43 MB)
    char* w = (char*)d_ws;
    unsigned short* Qhi = (unsigned short*)w;            w += (size_t)QUEUE * DIM * 2;     // 32 MB
    unsigned long long* cand = (unsigned long long*)w;   w += (size_t)MROWS * NTILE * 8;   // 4 MB
    unsigned long long* rowbest  = (unsigned long long*)w; w += MROWS * 8;
    unsigned long long* rowfinal = (unsigned long long*)w; w += MROWS * 8;
    float* Pn  = (float*)w;                              w += (size_t)MROWS * DIM * 4;     // 1 MB
    float* PnT = (float*)w;                              w += (size_t)MROWS * DIM * 4;     // 1 MB
    unsigned short* Phi = (unsigned short*)w;            w += (size_t)MROWS * DIM * 2;     // 0.5 MB
    float* S = (float*)w;                                w += (size_t)2 * BATCH * BATCH * 4; // 2 MB
    unsigned int* pairs = (unsigned int*)w;              w += (size_t)MROWS * NTILE * 4;   // 2 MB
    int* npairs = (int*)w;                               w += 256;
    int* nnidx  = (int*)w;

    hipLaunchKernelGGL(k0_qprep,    dim3(QUEUE * DIM / 4 / 256), dim3(256), 0, stream, queue, Qhi, outq);
    hipLaunchKernelGGL(k1_norm,     dim3(MROWS), dim3(64),  0, stream, p1, p2, Pn, PnT, Phi, outq);
    hipLaunchKernelGGL(k2_mfma,     dim3(2 * NTILE), dim3(256), 0, stream, Phi, Qhi, cand);
    hipLaunchKernelGGL(k2b_rowmax,  dim3(MROWS), dim3(64),  0, stream, cand, rowbest, rowfinal, npairs);
    hipLaunchKernelGGL(k2c_list,    dim3(MROWS * NTILE / 256), dim3(256), 0, stream, cand, rowbest, pairs, npairs);
    hipLaunchKernelGGL(k2d_rescore, dim3(1024),  dim3(256), 0, stream, pairs, npairs, Pn, queue, rowfinal);
    hipLaunchKernelGGL(k2e_final,   dim3(4),     dim3(256), 0, stream, rowfinal, nnidx);
    hipLaunchKernelGGL(k3_sim,      dim3(MROWS), dim3(256), 0, stream, nnidx, queue, PnT, S);
    hipLaunchKernelGGL(k4_loss,     dim3(4 * BATCH), dim3(256), 0, stream, S, loss);
}

// Round 4
// 355.805 us; speedup vs baseline: 3.9134x; 1.1967x over previous
//
#include <hip/hip_runtime.h>
#include <stdint.h>

// NNCLR forward on MI355X — round 4.
// Changes vs round 3:
//  * k2: block = n-tile(128). B staged once to 64KB LDS (XOR-swizzled, conflict-free frag reads)
//    with FUSED fp32->bf16 convert (k0 deleted) and FUSED new_queue FIFO copy.
//    A frags from L2-resident Phi. ks-loop unroll bounded (round-3 spill fix: no tight
//    launch_bounds + full unroll). Epilogue at 32-col granularity via float shfl reductions.
//  * rescore: granularity 128 -> 32 cols per candidate group (4x less rescore traffic),
//    one WAVE per (row,group) pair.
//  * k3: 8 rows per block (8x less PnT re-read, vectorized LDS reads).

#define BATCH  512
#define DIM    256
#define QUEUE  65536
#define MROWS  1024
#define NGRP   2048          // 65536 / 32 candidate groups
#define MARGIN 0.01f         // > 2*bf16 dot err bound (7.8e-3) for unit vectors

typedef short bf16x8 __attribute__((ext_vector_type(8)));
typedef float f32x4  __attribute__((ext_vector_type(4)));

__device__ __forceinline__ unsigned int mono_f32(float f) {
    unsigned int u = __float_as_uint(f);
    return (u & 0x80000000u) ? ~u : (u | 0x80000000u);
}
__device__ __forceinline__ float unmono_f32(unsigned int m) {
    unsigned int u = (m & 0x80000000u) ? (m ^ 0x80000000u) : ~m;
    return __uint_as_float(u);
}
__device__ __forceinline__ unsigned short f2bf(float f) {   // RNE fp32->bf16
    unsigned int u = __float_as_uint(f);
    return (unsigned short)((u + 0x7fffu + ((u >> 16) & 1u)) >> 16);
}

// ---------------- k1: normalize ----------------
__global__ void k1_norm(const float* __restrict__ p1, const float* __restrict__ p2,
                        float* __restrict__ Pn, float* __restrict__ PnT,
                        unsigned short* __restrict__ Phi, float* __restrict__ outq)
{
    const int r = blockIdx.x;        // 0..1023
    const int t = threadIdx.x;       // 0..63
    const float* src = (r < BATCH) ? p1 : p2;
    const int row = (r < BATCH) ? r : r - BATCH;
    float4 v = ((const float4*)(src + (size_t)row * DIM))[t];
    float sq = v.x*v.x + v.y*v.y + v.z*v.z + v.w*v.w;
    #pragma unroll
    for (int off = 32; off; off >>= 1) sq += __shfl_xor(sq, off, 64);
    sq = fmaxf(sq, 1e-12f);
    float s = rsqrtf(sq);
    s = s * (1.5f - 0.5f * sq * s * s);
    v.x *= s; v.y *= s; v.z *= s; v.w *= s;
    ((float4*)(Pn + (size_t)r * DIM))[t] = v;
    const int k = t * 4;
    PnT[(size_t)(k + 0) * MROWS + r] = v.x;
    PnT[(size_t)(k + 1) * MROWS + r] = v.y;
    PnT[(size_t)(k + 2) * MROWS + r] = v.z;
    PnT[(size_t)(k + 3) * MROWS + r] = v.w;
    short4 b;
    b.x = (short)f2bf(v.x); b.y = (short)f2bf(v.y);
    b.z = (short)f2bf(v.z); b.w = (short)f2bf(v.w);
    ((short4*)Phi)[(size_t)r * (DIM / 4) + t] = b;
    if (r < BATCH) ((float4*)(outq + (size_t)r * DIM))[t] = v;  // new_queue[0:512] = p1n
}

// ---------------- k2: bf16 MFMA filter + fused convert + fused FIFO copy ----------------
// 512 blocks, one per 128-col queue tile. LDS B layout: 16B chunk (r, c16) at
// r*512 + ((c16 ^ (r & 31)) << 4)  — frag reads land 2-way/bank = free.
__global__ __launch_bounds__(256, 2)
void k2_mfma(const unsigned short* __restrict__ Phi, const float* __restrict__ queue,
             float* __restrict__ outq, unsigned long long* __restrict__ cand)
{
    __shared__ __align__(16) char Bs[65536];
    const int nt = blockIdx.x;       // 0..511
    const int n0 = nt * 128;
    const int t  = threadIdx.x;
    const int w  = t >> 6, lane = t & 63;
    const int wm = w & 1, wn = w >> 1;
    const int lr = lane & 15, q = lane >> 4;

    // ---- stage: read queue fp32 tile (coalesced), FIFO-copy to outq, cvt bf16 -> swizzled LDS
    {
        const float4* qsrc = (const float4*)(queue + (size_t)n0 * DIM);
        float4* qdst = (float4*)(outq + (size_t)(n0 + BATCH) * DIM);
        #pragma unroll 4
        for (int it = 0; it < 32; ++it) {
            const int L = it * 256 + t;          // 0..8191 ; r is wave-uniform, h = lane
            const int r = L >> 6, h = L & 63;
            float4 v = qsrc[(size_t)r * 64 + h];
            if (n0 + r < QUEUE - BATCH) qdst[(size_t)r * 64 + h] = v;
            short4 b;
            b.x = (short)f2bf(v.x); b.y = (short)f2bf(v.y);
            b.z = (short)f2bf(v.z); b.w = (short)f2bf(v.w);
            const int c16 = h >> 1, half = h & 1;
            *(short4*)(Bs + r * 512 + ((c16 ^ (r & 31)) << 4) + half * 8) = b;
        }
    }
    __syncthreads();

    const unsigned short* Aw = Phi + (size_t)(wm * 64 + lr) * DIM + q * 8;

    for (int mt = 0; mt < 8; ++mt) {
        const int m0 = mt * 128;
        f32x4 acc[4][4];
        #pragma unroll
        for (int i = 0; i < 4; ++i)
            #pragma unroll
            for (int j = 0; j < 4; ++j) acc[i][j] = (f32x4){0.f, 0.f, 0.f, 0.f};

        const unsigned short* Amt = Aw + (size_t)m0 * DIM;
        #pragma unroll 2
        for (int ks = 0; ks < 8; ++ks) {
            bf16x8 a[4], b[4];
            #pragma unroll
            for (int mi = 0; mi < 4; ++mi)
                a[mi] = *(const bf16x8*)(Amt + (size_t)mi * 16 * DIM + ks * 32);
            #pragma unroll
            for (int ni = 0; ni < 4; ++ni) {
                const int r = wn * 64 + ni * 16 + lr;
                const int c16 = ks * 4 + q;
                b[ni] = *(const bf16x8*)(Bs + r * 512 + ((c16 ^ (r & 31)) << 4));
            }
            #pragma unroll
            for (int mi = 0; mi < 4; ++mi)
                #pragma unroll
                for (int ni = 0; ni < 4; ++ni)
                    acc[mi][ni] = __builtin_amdgcn_mfma_f32_16x16x32_bf16(a[mi], b[ni], acc[mi][ni], 0, 0, 0);
        }

        // ---- epilogue: per-row max at 32-col granularity; C/D: col=lane&15, row=q*4+reg
        #pragma unroll
        for (int mi = 0; mi < 4; ++mi) {
            #pragma unroll
            for (int reg = 0; reg < 4; ++reg) {
                const int row = m0 + wm * 64 + mi * 16 + q * 4 + reg;
                #pragma unroll
                for (int p = 0; p < 2; ++p) {
                    const float v0 = acc[mi][2 * p][reg];
                    const float v1 = acc[mi][2 * p + 1][reg];
                    float gm = fmaxf(v0, v1);
                    #pragma unroll
                    for (int off = 1; off <= 8; off <<= 1) gm = fmaxf(gm, __shfl_xor(gm, off, 64));
                    unsigned int c0 = (v0 == gm) ? (unsigned int)(n0 + wn * 64 + (2 * p) * 16 + lr) : 0xFFFFu;
                    unsigned int c1 = (v1 == gm) ? (unsigned int)(n0 + wn * 64 + (2 * p + 1) * 16 + lr) : 0xFFFFu;
                    unsigned int cm = c0 < c1 ? c0 : c1;
                    #pragma unroll
                    for (int off = 1; off <= 8; off <<= 1) {
                        unsigned int o = __shfl_xor(cm, off, 64);
                        cm = cm < o ? cm : o;
                    }
                    if (lr == 0) {
                        unsigned long long pk = ((unsigned long long)mono_f32(gm) << 32)
                                              | (unsigned int)(65535 - cm);
                        cand[(size_t)row * NGRP + (nt * 4 + wn * 2 + p)] = pk;
                    }
                }
            }
        }
    }
}

// ---------------- k2b: per-row max + init ----------------
__global__ void k2b_rowmax(const unsigned long long* __restrict__ cand,
                           unsigned long long* __restrict__ rowbest,
                           unsigned long long* __restrict__ rowfinal,
                           int* __restrict__ npairs)
{
    const int row = blockIdx.x;      // 0..1023
    const int t = threadIdx.x;       // 64
    unsigned long long best = 0ull;
    for (int i = t; i < NGRP; i += 64) {
        unsigned long long c = cand[(size_t)row * NGRP + i];
        best = best > c ? best : c;
    }
    #pragma unroll
    for (int off = 1; off < 64; off <<= 1) {
        unsigned long long o = __shfl_xor(best, off, 64);
        best = best > o ? best : o;
    }
    if (t == 0) {
        rowbest[row] = best;
        rowfinal[row] = 0ull;        // ws re-poisoned 0xAA every call — must re-init
        if (row == 0) *npairs = 0;
    }
}

// ---------------- k2c: compact (row,group) pairs within margin ----------------
__global__ void k2c_list(const unsigned long long* __restrict__ cand,
                         const unsigned long long* __restrict__ rowbest,
                         unsigned int* __restrict__ pairs, int* __restrict__ npairs)
{
    const int idx = blockIdx.x * 256 + threadIdx.x;   // 0 .. 1024*2048-1
    const int row = idx >> 11, g = idx & (NGRP - 1);
    const unsigned int thrm = mono_f32(unmono_f32((unsigned int)(rowbest[row] >> 32)) - MARGIN);
    if ((unsigned int)(cand[idx] >> 32) >= thrm) {
        int p = atomicAdd(npairs, 1);
        pairs[p] = ((unsigned int)row << 16) | (unsigned int)g;
    }
}

// ---------------- k2d: exact fp32 rescore, one wave per (row,group) ----------------
__global__ __launch_bounds__(256, 4)
void k2d_rescore(const unsigned int* __restrict__ pairs, const int* __restrict__ npairs,
                 const float* __restrict__ Pn, const float* __restrict__ queue,
                 unsigned long long* __restrict__ rowfinal)
{
    const int t = threadIdx.x, w = t >> 6, lane = t & 63;
    const int n = *npairs;
    const int col_l = lane & 31, half = lane >> 5;
    for (int p = blockIdx.x * 4 + w; p < n; p += gridDim.x * 4) {
        const unsigned int pr = pairs[p];
        const int row = pr >> 16, g = pr & 0xffff;
        const int col = g * 32 + col_l;
        const float4* qp = (const float4*)(queue + (size_t)col * DIM + half * 128);
        const float4* pp = (const float4*)(Pn + (size_t)row * DIM + half * 128);
        float4 sv = {0.f, 0.f, 0.f, 0.f};
        #pragma unroll 8
        for (int j = 0; j < 32; ++j) {
            float4 a = pp[j], b = qp[j];
            sv.x = fmaf(a.x, b.x, sv.x); sv.y = fmaf(a.y, b.y, sv.y);
            sv.z = fmaf(a.z, b.z, sv.z); sv.w = fmaf(a.w, b.w, sv.w);
        }
        float s = (sv.x + sv.y) + (sv.z + sv.w);
        s += __shfl_xor(s, 32, 64);                       // combine k-halves
        unsigned long long best = ((unsigned long long)mono_f32(s) << 32)
                                | (unsigned int)(65535 - col);
        #pragma unroll
        for (int off = 1; off <= 16; off <<= 1) {
            unsigned long long o = __shfl_xor(best, off, 64);
            best = best > o ? best : o;
        }
        if (lane == 0) atomicMax(rowfinal + row, best);
    }
}

// ---------------- k2e: extract nn indices ----------------
__global__ void k2e_final(const unsigned long long* __restrict__ rowfinal, int* __restrict__ nnidx)
{
    const int i = blockIdx.x * 256 + threadIdx.x;
    if (i < MROWS) nnidx[i] = 65535 - (int)(rowfinal[i] & 0xFFFFull);
}

// ---------------- k3: S1/S2 similarity matrices (8 rows/block) ----------------
__global__ void k3_sim(const int* __restrict__ nnidx, const float* __restrict__ queue,
                       const float* __restrict__ PnT, float* __restrict__ S)
{
    const int rb = blockIdx.x * 8;   // 0..1016 (rows of [nn1;nn2])
    const int tid = threadIdx.x;     // 256
    const int which = (rb < BATCH) ? 0 : 1;
    const int colbase = which ? 0 : BATCH;    // S1 vs p2 (cols 512..1023), S2 vs p1 (0..511)
    __shared__ float nnv[8][DIM];
    #pragma unroll
    for (int j = 0; j < 8; ++j)
        nnv[j][tid] = queue[(size_t)nnidx[rb + j] * DIM + tid];
    __syncthreads();
    float acc0[8], acc1[8];
    #pragma unroll
    for (int j = 0; j < 8; ++j) { acc0[j] = 0.f; acc1[j] = 0.f; }
    for (int k4 = 0; k4 < 64; ++k4) {
        float4 nv[8];
        #pragma unroll
        for (int j = 0; j < 8; ++j) nv[j] = ((const float4*)nnv[j])[k4];
        #pragma unroll
        for (int kk = 0; kk < 4; ++kk) {
            const int k = k4 * 4 + kk;
            const float v0 = PnT[(size_t)k * MROWS + colbase + tid];
            const float v1 = PnT[(size_t)k * MROWS + colbase + tid + 256];
            #pragma unroll
            for (int j = 0; j < 8; ++j) {
                const float nj = ((const float*)&nv[j])[kk];
                acc0[j] = fmaf(nj, v0, acc0[j]);
                acc1[j] = fmaf(nj, v1, acc1[j]);
            }
        }
    }
    const int i0 = rb & (BATCH - 1);
    float* Sout = S + (size_t)which * (BATCH * BATCH);
    #pragma unroll
    for (int j = 0; j < 8; ++j) {
        Sout[(size_t)(i0 + j) * BATCH + tid]       = acc0[j] * 10.0f;
        Sout[(size_t)(i0 + j) * BATCH + tid + 256] = acc1[j] * 10.0f;
    }
}

// ---------------- k4: loss ----------------
__global__ void k4_loss(const float* __restrict__ S, float* __restrict__ loss)
{
    const int r = blockIdx.x;        // 0..2047
    const int tid = threadIdx.x;     // 256
    const int grp = r >> 9;
    const int i = r & 511;
    const float* M = S + (size_t)(grp >> 1) * (BATCH * BATCH);
    float x0, x1;
    if (!(grp & 1)) { x0 = M[(size_t)i * BATCH + tid];  x1 = M[(size_t)i * BATCH + tid + 256]; }
    else            { x0 = M[(size_t)tid * BATCH + i];  x1 = M[(size_t)(tid + 256) * BATCH + i]; }
    const float diag = M[(size_t)i * BATCH + i];
    float mx = fmaxf(x0, x1);
    #pragma unroll
    for (int off = 1; off < 64; off <<= 1) mx = fmaxf(mx, __shfl_xor(mx, off, 64));
    __shared__ float redm[4], reds[4];
    if ((tid & 63) == 0) redm[tid >> 6] = mx;
    __syncthreads();
    mx = fmaxf(fmaxf(redm[0], redm[1]), fmaxf(redm[2], redm[3]));
    float e = __expf(x0 - mx) + __expf(x1 - mx);
    #pragma unroll
    for (int off = 1; off < 64; off <<= 1) e += __shfl_xor(e, off, 64);
    if ((tid & 63) == 0) reds[tid >> 6] = e;
    __syncthreads();
    if (tid == 0)
        loss[r] = mx + logf(reds[0] + reds[1] + reds[2] + reds[3]) - diag;
}

// ---------------- launcher ----------------
extern "C" void kernel_launch(void* const* d_in, const int* in_sizes, int n_in,
                              void* d_out, int out_size, void* d_ws, size_t ws_size,
                              hipStream_t stream)
{
    const float* p1    = (const float*)d_in[0];
    const float* p2    = (const float*)d_in[1];
    const float* queue = (const float*)d_in[2];
    float* out  = (float*)d_out;
    float* loss = out;
    float* outq = out + 4 * BATCH;

    // Workspace (~28.6 MB; ws >= 42.6 MB proven in round 2)
    char* w = (char*)d_ws;
    unsigned long long* cand = (unsigned long long*)w;     w += (size_t)MROWS * NGRP * 8;   // 16 MB
    unsigned long long* rowbest  = (unsigned long long*)w; w += MROWS * 8;
    unsigned long long* rowfinal = (unsigned long long*)w; w += MROWS * 8;
    float* Pn  = (float*)w;                                w += (size_t)MROWS * DIM * 4;    // 1 MB
    float* PnT = (float*)w;                                w += (size_t)MROWS * DIM * 4;    // 1 MB
    unsigned short* Phi = (unsigned short*)w;              w += (size_t)MROWS * DIM * 2;    // 0.5 MB
    float* S = (float*)w;                                  w += (size_t)2 * BATCH * BATCH * 4; // 2 MB
    unsigned int* pairs = (unsigned int*)w;                w += (size_t)MROWS * NGRP * 4;   // 8 MB (worst case)
    int* npairs = (int*)w;                                 w += 256;
    int* nnidx  = (int*)w;

    hipLaunchKernelGGL(k1_norm,     dim3(MROWS), dim3(64),  0, stream, p1, p2, Pn, PnT, Phi, outq);
    hipLaunchKernelGGL(k2_mfma,     dim3(QUEUE / 128), dim3(256), 0, stream, Phi, queue, outq, cand);
    hipLaunchKernelGGL(k2b_rowmax,  dim3(MROWS), dim3(64),  0, stream, cand, rowbest, rowfinal, npairs);
    hipLaunchKernelGGL(k2c_list,    dim3(MROWS * NGRP / 256), dim3(256), 0, stream, cand, rowbest, pairs, npairs);
    hipLaunchKernelGGL(k2d_rescore, dim3(512),   dim3(256), 0, stream, pairs, npairs, Pn, queue, rowfinal);
    hipLaunchKernelGGL(k2e_final,   dim3(4),     dim3(256), 0, stream, rowfinal, nnidx);
    hipLaunchKernelGGL(k3_sim,      dim3(MROWS / 8), dim3(256), 0, stream, nnidx, queue, PnT, S);
    hipLaunchKernelGGL(k4_loss,     dim3(4 * BATCH), dim3(256), 0, stream, S, loss);
}